// Round 4
// baseline (687.594 us; speedup 1.0000x reference)
//
#include <hip/hip_runtime.h>

#define IN_CH 128
#define OUT_CH 256
#define BLK_SCAN 1024

// fused: zero count + transpose W (Wt[c][t] = W[t][c], 128KB)
__global__ void init_kernel(const float* __restrict__ W, float* __restrict__ Wt,
                            int* __restrict__ count, int N) {
  int i = blockIdx.x * blockDim.x + threadIdx.x;
  if (i < N) count[i] = 0;
  if (i < IN_CH * OUT_CH) {
    int c = i >> 8;
    int t = i & (OUT_CH - 1);
    Wt[i] = W[t * IN_CH + c];
  }
}

__global__ void hist_kernel(const int* __restrict__ col, int E, int* __restrict__ count) {
  int i = blockIdx.x * blockDim.x + threadIdx.x;
  if (i < E) atomicAdd(&count[col[i]], 1);
}

// shfl-based block scan: 3 barriers
__global__ __launch_bounds__(BLK_SCAN) void scan_block_kernel(
    const int* __restrict__ count, int N, int* __restrict__ excl, int* __restrict__ bsum) {
  __shared__ int wsum[16];
  const int tid = threadIdx.x;
  const int i = blockIdx.x * BLK_SCAN + tid;
  const int v = (i < N) ? count[i] : 0;
  int x = v;
#pragma unroll
  for (int d = 1; d < 64; d <<= 1) {
    int t = __shfl_up(x, d, 64);
    if ((tid & 63) >= d) x += t;
  }
  if ((tid & 63) == 63) wsum[tid >> 6] = x;
  __syncthreads();
  if (tid < 16) {
    int s = wsum[tid];
#pragma unroll
    for (int d = 1; d < 16; d <<= 1) {
      int t = __shfl_up(s, d, 16);
      if (tid >= d) s += t;
    }
    wsum[tid] = s;
  }
  __syncthreads();
  const int w = tid >> 6;
  const int prefix = (w == 0) ? 0 : wsum[w - 1];
  if (i < N) excl[i] = prefix + x - v;
  if (tid == BLK_SCAN - 1) bsum[blockIdx.x] = prefix + x;
}

__global__ void scan_bsum_kernel(int* __restrict__ bsum, int nb) {
  __shared__ int tmp[256];
  const int tid = threadIdx.x;
  int run = 0;
  for (int s = 0; s < nb; s += 256) {
    int v = (s + tid < nb) ? bsum[s + tid] : 0;
    tmp[tid] = v;
    __syncthreads();
    for (int d = 1; d < 256; d <<= 1) {
      int t = (tid >= d) ? tmp[tid - d] : 0;
      __syncthreads();
      tmp[tid] += t;
      __syncthreads();
    }
    if (s + tid < nb) bsum[s + tid] = run + tmp[tid] - v;
    run += tmp[255];
    __syncthreads();
  }
}

__global__ void add_offsets_kernel(int* __restrict__ excl, const int* __restrict__ bsum,
                                   int* __restrict__ cursor, int N) {
  int i = blockIdx.x * blockDim.x + threadIdx.x;
  if (i < N) {
    int o = excl[i] + bsum[i / BLK_SCAN];
    excl[i] = o;
    cursor[i] = o;
  }
}

__global__ void scatter_kernel(const int* __restrict__ col, int E,
                               int* __restrict__ cursor, int* __restrict__ sorted) {
  int i = blockIdx.x * blockDim.x + threadIdx.x;
  if (i < E) {
    int c = col[i];
    int pos = atomicAdd(&cursor[c], 1);
    sorted[pos] = i;
  }
}

// One node per wave; 16 rows in flight per iteration (64 lanes x float2 = 512B row).
// Writes the 128-ch fp32 sum to agg[n][:].
__global__ __launch_bounds__(256) void aggregate_kernel(
    const float* __restrict__ te, const int* __restrict__ offsets,
    const int* __restrict__ cend, const int* __restrict__ sorted,
    float* __restrict__ agg, int N) {
  const int g    = threadIdx.x >> 6;
  const int lane = threadIdx.x & 63;
  const int n = blockIdx.x * 4 + g;
  if (n >= N) return;

  float ax = 0.f, ay = 0.f;
  const int s = offsets[n];
  const int e = cend[n];
  const size_t co = (size_t)(lane * 2);
  if (s < e) {
    int my = 0;
    if (lane < 16) {
      int idx = s + lane;
      my = sorted[idx < e ? idx : (e - 1)];
    }
    for (int i = s; i < e; i += 16) {
#define EID(j) __shfl(my, j, 64)
      const float2 t0  = *(const float2*)(te + (size_t)EID(0)  * IN_CH + co);
      const float2 t1  = *(const float2*)(te + (size_t)EID(1)  * IN_CH + co);
      const float2 t2  = *(const float2*)(te + (size_t)EID(2)  * IN_CH + co);
      const float2 t3  = *(const float2*)(te + (size_t)EID(3)  * IN_CH + co);
      const float2 t4  = *(const float2*)(te + (size_t)EID(4)  * IN_CH + co);
      const float2 t5  = *(const float2*)(te + (size_t)EID(5)  * IN_CH + co);
      const float2 t6  = *(const float2*)(te + (size_t)EID(6)  * IN_CH + co);
      const float2 t7  = *(const float2*)(te + (size_t)EID(7)  * IN_CH + co);
      const float2 t8  = *(const float2*)(te + (size_t)EID(8)  * IN_CH + co);
      const float2 t9  = *(const float2*)(te + (size_t)EID(9)  * IN_CH + co);
      const float2 t10 = *(const float2*)(te + (size_t)EID(10) * IN_CH + co);
      const float2 t11 = *(const float2*)(te + (size_t)EID(11) * IN_CH + co);
      const float2 t12 = *(const float2*)(te + (size_t)EID(12) * IN_CH + co);
      const float2 t13 = *(const float2*)(te + (size_t)EID(13) * IN_CH + co);
      const float2 t14 = *(const float2*)(te + (size_t)EID(14) * IN_CH + co);
      const float2 t15 = *(const float2*)(te + (size_t)EID(15) * IN_CH + co);
#undef EID
      // prefetch next sorted batch while row loads are in flight
      int nxt = 0;
      {
        const int ib = i + 16;
        if (lane < 16 && ib < e) {
          int idx = ib + lane;
          nxt = sorted[idx < e ? idx : (e - 1)];
        }
      }
      const int rem = e - i;  // wave-uniform
      if (rem >= 16) {
        ax += (t0.x + t1.x) + (t2.x + t3.x) + (t4.x + t5.x) + (t6.x + t7.x) +
              (t8.x + t9.x) + (t10.x + t11.x) + (t12.x + t13.x) + (t14.x + t15.x);
        ay += (t0.y + t1.y) + (t2.y + t3.y) + (t4.y + t5.y) + (t6.y + t7.y) +
              (t8.y + t9.y) + (t10.y + t11.y) + (t12.y + t13.y) + (t14.y + t15.y);
      } else {
        ax += t0.x; ay += t0.y;
#define ACC(j, tj) { const float c = (rem > j) ? 1.f : 0.f; \
                     ax = fmaf(c, tj.x, ax); ay = fmaf(c, tj.y, ay); }
        ACC(1, t1)  ACC(2, t2)  ACC(3, t3)  ACC(4, t4)  ACC(5, t5)
        ACC(6, t6)  ACC(7, t7)  ACC(8, t8)  ACC(9, t9)  ACC(10, t10)
        ACC(11, t11) ACC(12, t12) ACC(13, t13) ACC(14, t14) ACC(15, t15)
#undef ACC
      }
      my = nxt;
    }
  }
  float2 r; r.x = ax; r.y = ay;
  *(float2*)(agg + (size_t)n * IN_CH + co) = r;
}

// 16 nodes per block; thread = channel PAIR (float2 acc -> packed fp32 FMA),
// half 0 -> nodes 0..7, half 1 -> nodes 8..15. agg loads are wave-uniform
// (scalar-cache broadcast); Wt/out accesses fully coalesced.
#define PNB 16
__global__ __launch_bounds__(256) void project_kernel(
    const float* __restrict__ agg, const float* __restrict__ Wt,
    const float* __restrict__ bias, float* __restrict__ out, int N) {
  const int ch2  = threadIdx.x & 127;
  const int half = threadIdx.x >> 7;
  const int base = blockIdx.x * PNB + half * 8;
  float2 acc[8];
#pragma unroll
  for (int gg = 0; gg < 8; ++gg) { acc[gg].x = 0.f; acc[gg].y = 0.f; }

  if (base + 8 <= N) {
#pragma unroll 4
    for (int c4 = 0; c4 < IN_CH / 4; ++c4) {
      const int c = c4 * 4;
      const float2 w0 = *(const float2*)(Wt + (size_t)(c + 0) * OUT_CH + ch2 * 2);
      const float2 w1 = *(const float2*)(Wt + (size_t)(c + 1) * OUT_CH + ch2 * 2);
      const float2 w2 = *(const float2*)(Wt + (size_t)(c + 2) * OUT_CH + ch2 * 2);
      const float2 w3 = *(const float2*)(Wt + (size_t)(c + 3) * OUT_CH + ch2 * 2);
#pragma unroll
      for (int gg = 0; gg < 8; ++gg) {
        const float4 a = *(const float4*)(agg + (size_t)(base + gg) * IN_CH + c);
        acc[gg].x = fmaf(a.x, w0.x, fmaf(a.y, w1.x, fmaf(a.z, w2.x, fmaf(a.w, w3.x, acc[gg].x))));
        acc[gg].y = fmaf(a.x, w0.y, fmaf(a.y, w1.y, fmaf(a.z, w2.y, fmaf(a.w, w3.y, acc[gg].y))));
      }
    }
  } else {
#pragma unroll 4
    for (int c4 = 0; c4 < IN_CH / 4; ++c4) {
      const int c = c4 * 4;
      const float2 w0 = *(const float2*)(Wt + (size_t)(c + 0) * OUT_CH + ch2 * 2);
      const float2 w1 = *(const float2*)(Wt + (size_t)(c + 1) * OUT_CH + ch2 * 2);
      const float2 w2 = *(const float2*)(Wt + (size_t)(c + 2) * OUT_CH + ch2 * 2);
      const float2 w3 = *(const float2*)(Wt + (size_t)(c + 3) * OUT_CH + ch2 * 2);
#pragma unroll
      for (int gg = 0; gg < 8; ++gg) {
        const int nn = (base + gg < N) ? (base + gg) : (N > 0 ? N - 1 : 0);
        const float4 a = *(const float4*)(agg + (size_t)nn * IN_CH + c);
        acc[gg].x = fmaf(a.x, w0.x, fmaf(a.y, w1.x, fmaf(a.z, w2.x, fmaf(a.w, w3.x, acc[gg].x))));
        acc[gg].y = fmaf(a.x, w0.y, fmaf(a.y, w1.y, fmaf(a.z, w2.y, fmaf(a.w, w3.y, acc[gg].y))));
      }
    }
  }

  const float2 bv = *(const float2*)(bias + ch2 * 2);
#pragma unroll
  for (int gg = 0; gg < 8; ++gg) {
    const int nn = base + gg;
    if (nn < N) {
      float2 r; r.x = acc[gg].x + bv.x; r.y = acc[gg].y + bv.y;
      *(float2*)(out + (size_t)nn * OUT_CH + ch2 * 2) = r;
    }
  }
}

extern "C" void kernel_launch(void* const* d_in, const int* in_sizes, int n_in,
                              void* d_out, int out_size, void* d_ws, size_t ws_size,
                              hipStream_t stream) {
  const int* edge_index = (const int*)d_in[0];
  const float* te       = (const float*)d_in[1];
  const float* W        = (const float*)d_in[3];
  const float* bias     = (const float*)d_in[4];
  float* out            = (float*)d_out;

  const int E = in_sizes[0] / 2;
  const int N = out_size / OUT_CH;
  const int* col = edge_index + E;

  int* ws      = (int*)d_ws;
  int* count   = ws;                        // N
  int* offsets = ws + N;                    // N
  int* cursor  = ws + 2 * N;                // N
  int* bsum    = ws + 3 * N;                // 4096
  int* sorted  = ws + 3 * N + 4096;         // E
  float* Wt    = (float*)(ws + 3 * N + 4096 + E);          // 32768 floats
  float* agg   = (float*)(ws + 3 * N + 4096 + E + 32768);  // N*128 floats

  const int nb = (N + BLK_SCAN - 1) / BLK_SCAN;
  const int init_n = (N > IN_CH * OUT_CH) ? N : IN_CH * OUT_CH;

  hipLaunchKernelGGL(init_kernel, dim3((init_n + 255) / 256), dim3(256), 0, stream,
                     W, Wt, count, N);
  hipLaunchKernelGGL(hist_kernel, dim3((E + 255) / 256), dim3(256), 0, stream, col, E, count);
  hipLaunchKernelGGL(scan_block_kernel, dim3(nb), dim3(BLK_SCAN), 0, stream, count, N, offsets, bsum);
  hipLaunchKernelGGL(scan_bsum_kernel, dim3(1), dim3(256), 0, stream, bsum, nb);
  hipLaunchKernelGGL(add_offsets_kernel, dim3((N + 255) / 256), dim3(256), 0, stream,
                     offsets, bsum, cursor, N);
  hipLaunchKernelGGL(scatter_kernel, dim3((E + 255) / 256), dim3(256), 0, stream, col, E, cursor, sorted);
  hipLaunchKernelGGL(aggregate_kernel, dim3((N + 3) / 4), dim3(256), 0, stream,
                     te, offsets, cursor, sorted, agg, N);
  hipLaunchKernelGGL(project_kernel, dim3((N + PNB - 1) / PNB), dim3(256), 0, stream,
                     agg, Wt, bias, out, N);
}

// Round 5
// 448.567 us; speedup vs baseline: 1.5329x; 1.5329x over previous
//
#include <hip/hip_runtime.h>
#include <hip/hip_bf16.h>

#define IN_CH 128
#define OUT_CH 256
#define BLK_SCAN 1024

typedef __bf16 bf16x8 __attribute__((ext_vector_type(8)));
typedef float f32x4 __attribute__((ext_vector_type(4)));

__device__ inline unsigned short f2bf(float f) {
  union { float f; unsigned int u; } v; v.f = f;
  unsigned int u = v.u;
  u += 0x7FFFu + ((u >> 16) & 1u);   // round-to-nearest-even
  return (unsigned short)(u >> 16);
}

// fused init: zero count + build Bpack.
// Bpack element layout (ushort): idx = (((tn*4+ks)*4+kb)*16 + c)*8 + j
//   value = bf16( W[tn*16+c][ks*32 + kb*8 + j] )
// so lane (c + 16*kb) reads one contiguous bf16x8 per (tn, ks).
__global__ void init_kernel(const float* __restrict__ W, unsigned short* __restrict__ Bpack,
                            int* __restrict__ count, int N) {
  int i = blockIdx.x * blockDim.x + threadIdx.x;
  if (i < N) count[i] = 0;
  if (i < IN_CH * OUT_CH) {
    const int j  = i & 7;
    const int c  = (i >> 3) & 15;
    const int kb = (i >> 7) & 3;
    const int ks = (i >> 9) & 3;
    const int tn = i >> 11;
    const int row = tn * 16 + c;             // output channel
    const int k   = ks * 32 + kb * 8 + j;    // input channel
    Bpack[i] = f2bf(W[(size_t)row * IN_CH + k]);
  }
}

__global__ void hist_kernel(const int* __restrict__ col, int E, int* __restrict__ count) {
  int i = blockIdx.x * blockDim.x + threadIdx.x;
  if (i < E) atomicAdd(&count[col[i]], 1);
}

// shfl-based block scan: 3 barriers
__global__ __launch_bounds__(BLK_SCAN) void scan_block_kernel(
    const int* __restrict__ count, int N, int* __restrict__ excl, int* __restrict__ bsum) {
  __shared__ int wsum[16];
  const int tid = threadIdx.x;
  const int i = blockIdx.x * BLK_SCAN + tid;
  const int v = (i < N) ? count[i] : 0;
  int x = v;
#pragma unroll
  for (int d = 1; d < 64; d <<= 1) {
    int t = __shfl_up(x, d, 64);
    if ((tid & 63) >= d) x += t;
  }
  if ((tid & 63) == 63) wsum[tid >> 6] = x;
  __syncthreads();
  if (tid < 16) {
    int s = wsum[tid];
#pragma unroll
    for (int d = 1; d < 16; d <<= 1) {
      int t = __shfl_up(s, d, 16);
      if (tid >= d) s += t;
    }
    wsum[tid] = s;
  }
  __syncthreads();
  const int w = tid >> 6;
  const int prefix = (w == 0) ? 0 : wsum[w - 1];
  if (i < N) excl[i] = prefix + x - v;
  if (tid == BLK_SCAN - 1) bsum[blockIdx.x] = prefix + x;
}

__global__ void scan_bsum_kernel(int* __restrict__ bsum, int nb) {
  __shared__ int tmp[256];
  const int tid = threadIdx.x;
  int run = 0;
  for (int s = 0; s < nb; s += 256) {
    int v = (s + tid < nb) ? bsum[s + tid] : 0;
    tmp[tid] = v;
    __syncthreads();
    for (int d = 1; d < 256; d <<= 1) {
      int t = (tid >= d) ? tmp[tid - d] : 0;
      __syncthreads();
      tmp[tid] += t;
      __syncthreads();
    }
    if (s + tid < nb) bsum[s + tid] = run + tmp[tid] - v;
    run += tmp[255];
    __syncthreads();
  }
}

__global__ void add_offsets_kernel(int* __restrict__ excl, const int* __restrict__ bsum,
                                   int* __restrict__ cursor, int N) {
  int i = blockIdx.x * blockDim.x + threadIdx.x;
  if (i < N) {
    int o = excl[i] + bsum[i / BLK_SCAN];
    excl[i] = o;
    cursor[i] = o;
  }
}

__global__ void scatter_kernel(const int* __restrict__ col, int E,
                               int* __restrict__ cursor, int* __restrict__ sorted) {
  int i = blockIdx.x * blockDim.x + threadIdx.x;
  if (i < E) {
    int c = col[i];
    int pos = atomicAdd(&cursor[c], 1);
    sorted[pos] = i;
  }
}

// One node per wave; 16 rows in flight per iteration (64 lanes x float2 = 512B row).
// Writes the 128-ch sum as BF16 (row-major [N][128]) for the MFMA projection.
__global__ __launch_bounds__(256) void aggregate_kernel(
    const float* __restrict__ te, const int* __restrict__ offsets,
    const int* __restrict__ cend, const int* __restrict__ sorted,
    unsigned int* __restrict__ aggb32, int N) {
  const int g    = threadIdx.x >> 6;
  const int lane = threadIdx.x & 63;
  const int n = blockIdx.x * 4 + g;
  if (n >= N) return;

  float ax = 0.f, ay = 0.f;
  const int s = offsets[n];
  const int e = cend[n];
  const size_t co = (size_t)(lane * 2);
  if (s < e) {
    int my = 0;
    if (lane < 16) {
      int idx = s + lane;
      my = sorted[idx < e ? idx : (e - 1)];
    }
    for (int i = s; i < e; i += 16) {
#define EID(j) __shfl(my, j, 64)
      const float2 t0  = *(const float2*)(te + (size_t)EID(0)  * IN_CH + co);
      const float2 t1  = *(const float2*)(te + (size_t)EID(1)  * IN_CH + co);
      const float2 t2  = *(const float2*)(te + (size_t)EID(2)  * IN_CH + co);
      const float2 t3  = *(const float2*)(te + (size_t)EID(3)  * IN_CH + co);
      const float2 t4  = *(const float2*)(te + (size_t)EID(4)  * IN_CH + co);
      const float2 t5  = *(const float2*)(te + (size_t)EID(5)  * IN_CH + co);
      const float2 t6  = *(const float2*)(te + (size_t)EID(6)  * IN_CH + co);
      const float2 t7  = *(const float2*)(te + (size_t)EID(7)  * IN_CH + co);
      const float2 t8  = *(const float2*)(te + (size_t)EID(8)  * IN_CH + co);
      const float2 t9  = *(const float2*)(te + (size_t)EID(9)  * IN_CH + co);
      const float2 t10 = *(const float2*)(te + (size_t)EID(10) * IN_CH + co);
      const float2 t11 = *(const float2*)(te + (size_t)EID(11) * IN_CH + co);
      const float2 t12 = *(const float2*)(te + (size_t)EID(12) * IN_CH + co);
      const float2 t13 = *(const float2*)(te + (size_t)EID(13) * IN_CH + co);
      const float2 t14 = *(const float2*)(te + (size_t)EID(14) * IN_CH + co);
      const float2 t15 = *(const float2*)(te + (size_t)EID(15) * IN_CH + co);
#undef EID
      int nxt = 0;
      {
        const int ib = i + 16;
        if (lane < 16 && ib < e) {
          int idx = ib + lane;
          nxt = sorted[idx < e ? idx : (e - 1)];
        }
      }
      const int rem = e - i;  // wave-uniform
      if (rem >= 16) {
        ax += (t0.x + t1.x) + (t2.x + t3.x) + (t4.x + t5.x) + (t6.x + t7.x) +
              (t8.x + t9.x) + (t10.x + t11.x) + (t12.x + t13.x) + (t14.x + t15.x);
        ay += (t0.y + t1.y) + (t2.y + t3.y) + (t4.y + t5.y) + (t6.y + t7.y) +
              (t8.y + t9.y) + (t10.y + t11.y) + (t12.y + t13.y) + (t14.y + t15.y);
      } else {
        ax += t0.x; ay += t0.y;
#define ACC(j, tj) { const float c = (rem > j) ? 1.f : 0.f; \
                     ax = fmaf(c, tj.x, ax); ay = fmaf(c, tj.y, ay); }
        ACC(1, t1)  ACC(2, t2)  ACC(3, t3)  ACC(4, t4)  ACC(5, t5)
        ACC(6, t6)  ACC(7, t7)  ACC(8, t8)  ACC(9, t9)  ACC(10, t10)
        ACC(11, t11) ACC(12, t12) ACC(13, t13) ACC(14, t14) ACC(15, t15)
#undef ACC
      }
      my = nxt;
    }
  }
  // pack 2 channels (2*lane, 2*lane+1) -> one uint (little-endian: low = even ch)
  aggb32[(size_t)n * 64 + lane] = (unsigned int)f2bf(ax) | ((unsigned int)f2bf(ay) << 16);
}

// MFMA projection: C[N,256] = aggb[N,128] @ W^T + b.
// Block = 16 nodes x 256 cols; wave w covers cols [w*64, w*64+64).
// A frag: lane(r=lane&15, kb=lane>>4) holds aggb[m0+r][ks*32 + kb*8 .. +8]  (contiguous bf16x8)
// B frag: same (kb,j)->k convention from Bpack (built in init_kernel).
// k-permutation cancels because A and B use the identical convention.
// C/D: col=lane&15, row=(lane>>4)*4+reg  [HW-verified, guide §3]
__global__ __launch_bounds__(256) void project_mfma(
    const unsigned short* __restrict__ aggb, const unsigned short* __restrict__ Bpack,
    const float* __restrict__ bias, float* __restrict__ out, int N) {
  const int wave = threadIdx.x >> 6;
  const int lane = threadIdx.x & 63;
  const int r  = lane & 15;
  const int kb = lane >> 4;
  const int m0 = blockIdx.x * 16;

  bf16x8 a[4];
  const unsigned short* arow = aggb + (size_t)(m0 + r) * IN_CH + kb * 8;
#pragma unroll
  for (int ks = 0; ks < 4; ++ks)
    a[ks] = *(const bf16x8*)(arow + ks * 32);

  f32x4 acc[4];
#pragma unroll
  for (int ct = 0; ct < 4; ++ct) acc[ct] = (f32x4){0.f, 0.f, 0.f, 0.f};

#pragma unroll
  for (int ct = 0; ct < 4; ++ct) {
    const int tn = wave * 4 + ct;
#pragma unroll
    for (int ks = 0; ks < 4; ++ks) {
      const bf16x8 b = *(const bf16x8*)(Bpack + (size_t)((((tn * 4 + ks) * 4 + kb) * 16 + r) * 8));
      acc[ct] = __builtin_amdgcn_mfma_f32_16x16x32_bf16(a[ks], b, acc[ct], 0, 0, 0);
    }
  }

#pragma unroll
  for (int ct = 0; ct < 4; ++ct) {
    const int col = wave * 64 + ct * 16 + r;
    const float bv = bias[col];
#pragma unroll
    for (int j = 0; j < 4; ++j) {
      const int m = m0 + kb * 4 + j;
      if (m < N) out[(size_t)m * OUT_CH + col] = acc[ct][j] + bv;
    }
  }
}

extern "C" void kernel_launch(void* const* d_in, const int* in_sizes, int n_in,
                              void* d_out, int out_size, void* d_ws, size_t ws_size,
                              hipStream_t stream) {
  const int* edge_index = (const int*)d_in[0];
  const float* te       = (const float*)d_in[1];
  const float* W        = (const float*)d_in[3];
  const float* bias     = (const float*)d_in[4];
  float* out            = (float*)d_out;

  const int E = in_sizes[0] / 2;
  const int N = out_size / OUT_CH;
  const int* col = edge_index + E;

  // workspace layout (ints, each section padded to 16B)
  const int Np = (N + 3) & ~3;
  const int Ep = (E + 3) & ~3;
  int* ws      = (int*)d_ws;
  int* count   = ws;                          // Np
  int* offsets = ws + Np;                     // Np
  int* cursor  = ws + 2 * Np;                 // Np
  int* bsum    = ws + 3 * Np;                 // 4096
  int* sorted  = ws + 3 * Np + 4096;          // Ep
  unsigned short* Bpack = (unsigned short*)(ws + 3 * Np + 4096 + Ep);     // 32768 ushort = 16384 int
  unsigned int*   aggb  = (unsigned int*)(ws + 3 * Np + 4096 + Ep + 16384);  // N*64 uint

  const int nb = (N + BLK_SCAN - 1) / BLK_SCAN;
  const int init_n = (N > IN_CH * OUT_CH) ? N : IN_CH * OUT_CH;

  hipLaunchKernelGGL(init_kernel, dim3((init_n + 255) / 256), dim3(256), 0, stream,
                     W, Bpack, count, N);
  hipLaunchKernelGGL(hist_kernel, dim3((E + 255) / 256), dim3(256), 0, stream, col, E, count);
  hipLaunchKernelGGL(scan_block_kernel, dim3(nb), dim3(BLK_SCAN), 0, stream, count, N, offsets, bsum);
  hipLaunchKernelGGL(scan_bsum_kernel, dim3(1), dim3(256), 0, stream, bsum, nb);
  hipLaunchKernelGGL(add_offsets_kernel, dim3((N + 255) / 256), dim3(256), 0, stream,
                     offsets, bsum, cursor, N);
  hipLaunchKernelGGL(scatter_kernel, dim3((E + 255) / 256), dim3(256), 0, stream, col, E, cursor, sorted);
  hipLaunchKernelGGL(aggregate_kernel, dim3((N + 3) / 4), dim3(256), 0, stream,
                     te, offsets, cursor, sorted, aggb, N);
  hipLaunchKernelGGL(project_mfma, dim3((N + 15) / 16), dim3(256), 0, stream,
                     (const unsigned short*)aggb, Bpack, bias, out, N);
}

// Round 6
// 438.556 us; speedup vs baseline: 1.5679x; 1.0228x over previous
//
#include <hip/hip_runtime.h>
#include <hip/hip_bf16.h>

#define IN_CH 128
#define OUT_CH 256
#define BLK_SCAN 1024

typedef __bf16 bf16x8 __attribute__((ext_vector_type(8)));
typedef float f32x4 __attribute__((ext_vector_type(4)));

__device__ inline unsigned short f2bf(float f) {
  union { float f; unsigned int u; } v; v.f = f;
  unsigned int u = v.u;
  u += 0x7FFFu + ((u >> 16) & 1u);   // round-to-nearest-even
  return (unsigned short)(u >> 16);
}

// fused init: zero count + build Bpack.
// Bpack element layout (ushort): idx = (((tn*4+ks)*4+kb)*16 + c)*8 + j
//   value = bf16( W[tn*16+c][ks*32 + kb*8 + j] )
__global__ void init_kernel(const float* __restrict__ W, unsigned short* __restrict__ Bpack,
                            int* __restrict__ count, int N) {
  int i = blockIdx.x * blockDim.x + threadIdx.x;
  if (i < N) count[i] = 0;
  if (i < IN_CH * OUT_CH) {
    const int j  = i & 7;
    const int c  = (i >> 3) & 15;
    const int kb = (i >> 7) & 3;
    const int ks = (i >> 9) & 3;
    const int tn = i >> 11;
    const int row = tn * 16 + c;
    const int k   = ks * 32 + kb * 8 + j;
    Bpack[i] = f2bf(W[(size_t)row * IN_CH + k]);
  }
}

// 4 edges per thread, int4 read of col
__global__ void hist_kernel(const int* __restrict__ col, int E, int* __restrict__ count) {
  int i = blockIdx.x * blockDim.x + threadIdx.x;
  int b = i * 4;
  if (b + 4 <= E) {
    const int4 c = *(const int4*)(col + b);
    atomicAdd(&count[c.x], 1);
    atomicAdd(&count[c.y], 1);
    atomicAdd(&count[c.z], 1);
    atomicAdd(&count[c.w], 1);
  } else {
    for (int j = b; j < E; ++j) atomicAdd(&count[col[j]], 1);
  }
}

// shfl-based block scan: 3 barriers
__global__ __launch_bounds__(BLK_SCAN) void scan_block_kernel(
    const int* __restrict__ count, int N, int* __restrict__ excl, int* __restrict__ bsum) {
  __shared__ int wsum[16];
  const int tid = threadIdx.x;
  const int i = blockIdx.x * BLK_SCAN + tid;
  const int v = (i < N) ? count[i] : 0;
  int x = v;
#pragma unroll
  for (int d = 1; d < 64; d <<= 1) {
    int t = __shfl_up(x, d, 64);
    if ((tid & 63) >= d) x += t;
  }
  if ((tid & 63) == 63) wsum[tid >> 6] = x;
  __syncthreads();
  if (tid < 16) {
    int s = wsum[tid];
#pragma unroll
    for (int d = 1; d < 16; d <<= 1) {
      int t = __shfl_up(s, d, 16);
      if (tid >= d) s += t;
    }
    wsum[tid] = s;
  }
  __syncthreads();
  const int w = tid >> 6;
  const int prefix = (w == 0) ? 0 : wsum[w - 1];
  if (i < N) excl[i] = prefix + x - v;
  if (tid == BLK_SCAN - 1) bsum[blockIdx.x] = prefix + x;
}

__global__ void scan_bsum_kernel(int* __restrict__ bsum, int nb) {
  __shared__ int tmp[256];
  const int tid = threadIdx.x;
  int run = 0;
  for (int s = 0; s < nb; s += 256) {
    int v = (s + tid < nb) ? bsum[s + tid] : 0;
    tmp[tid] = v;
    __syncthreads();
    for (int d = 1; d < 256; d <<= 1) {
      int t = (tid >= d) ? tmp[tid - d] : 0;
      __syncthreads();
      tmp[tid] += t;
      __syncthreads();
    }
    if (s + tid < nb) bsum[s + tid] = run + tmp[tid] - v;
    run += tmp[255];
    __syncthreads();
  }
}

__global__ void add_offsets_kernel(int* __restrict__ excl, const int* __restrict__ bsum,
                                   int* __restrict__ cursor, int N) {
  int i = blockIdx.x * blockDim.x + threadIdx.x;
  if (i < N) {
    int o = excl[i] + bsum[i / BLK_SCAN];
    excl[i] = o;
    cursor[i] = o;
  }
}

// 4 edges per thread, int4 read of col
__global__ void scatter_kernel(const int* __restrict__ col, int E,
                               int* __restrict__ cursor, int* __restrict__ sorted) {
  int i = blockIdx.x * blockDim.x + threadIdx.x;
  int b = i * 4;
  if (b + 4 <= E) {
    const int4 c = *(const int4*)(col + b);
    int p0 = atomicAdd(&cursor[c.x], 1); sorted[p0] = b;
    int p1 = atomicAdd(&cursor[c.y], 1); sorted[p1] = b + 1;
    int p2 = atomicAdd(&cursor[c.z], 1); sorted[p2] = b + 2;
    int p3 = atomicAdd(&cursor[c.w], 1); sorted[p3] = b + 3;
  } else {
    for (int j = b; j < E; ++j) {
      int pos = atomicAdd(&cursor[col[j]], 1);
      sorted[pos] = j;
    }
  }
}

// One node per wave; 16 rows in flight per iteration.
// eids broadcast via READLANE -> SGPR base addressing (SALU, not per-lane v_mad_u64).
__global__ __launch_bounds__(256) void aggregate_kernel(
    const float* __restrict__ te, const int* __restrict__ offsets,
    const int* __restrict__ cend, const int* __restrict__ sorted,
    unsigned int* __restrict__ aggb32, int N) {
  const int g    = threadIdx.x >> 6;
  const int lane = threadIdx.x & 63;
  const int n = blockIdx.x * 4 + g;
  if (n >= N) return;

  float ax = 0.f, ay = 0.f;
  const int s = offsets[n];
  const int e = cend[n];
  const size_t co = (size_t)(lane * 2);
  if (s < e) {
    int my = 0;
    if (lane < 16) {
      int idx = s + lane;
      my = sorted[idx < e ? idx : (e - 1)];
    }
    for (int i = s; i < e; i += 16) {
#define EID(j) __builtin_amdgcn_readlane(my, j)
      const float2 t0  = *(const float2*)(te + (size_t)EID(0)  * IN_CH + co);
      const float2 t1  = *(const float2*)(te + (size_t)EID(1)  * IN_CH + co);
      const float2 t2  = *(const float2*)(te + (size_t)EID(2)  * IN_CH + co);
      const float2 t3  = *(const float2*)(te + (size_t)EID(3)  * IN_CH + co);
      const float2 t4  = *(const float2*)(te + (size_t)EID(4)  * IN_CH + co);
      const float2 t5  = *(const float2*)(te + (size_t)EID(5)  * IN_CH + co);
      const float2 t6  = *(const float2*)(te + (size_t)EID(6)  * IN_CH + co);
      const float2 t7  = *(const float2*)(te + (size_t)EID(7)  * IN_CH + co);
      const float2 t8  = *(const float2*)(te + (size_t)EID(8)  * IN_CH + co);
      const float2 t9  = *(const float2*)(te + (size_t)EID(9)  * IN_CH + co);
      const float2 t10 = *(const float2*)(te + (size_t)EID(10) * IN_CH + co);
      const float2 t11 = *(const float2*)(te + (size_t)EID(11) * IN_CH + co);
      const float2 t12 = *(const float2*)(te + (size_t)EID(12) * IN_CH + co);
      const float2 t13 = *(const float2*)(te + (size_t)EID(13) * IN_CH + co);
      const float2 t14 = *(const float2*)(te + (size_t)EID(14) * IN_CH + co);
      const float2 t15 = *(const float2*)(te + (size_t)EID(15) * IN_CH + co);
#undef EID
      // prefetch next sorted batch while row loads are in flight
      int nxt = 0;
      {
        const int ib = i + 16;
        if (lane < 16 && ib < e) {
          int idx = ib + lane;
          nxt = sorted[idx < e ? idx : (e - 1)];
        }
      }
      const int rem = e - i;  // wave-uniform
      if (rem >= 16) {
        ax += (t0.x + t1.x) + (t2.x + t3.x) + (t4.x + t5.x) + (t6.x + t7.x) +
              (t8.x + t9.x) + (t10.x + t11.x) + (t12.x + t13.x) + (t14.x + t15.x);
        ay += (t0.y + t1.y) + (t2.y + t3.y) + (t4.y + t5.y) + (t6.y + t7.y) +
              (t8.y + t9.y) + (t10.y + t11.y) + (t12.y + t13.y) + (t14.y + t15.y);
      } else {
        ax += t0.x; ay += t0.y;
#define ACC(j, tj) { const float c = (rem > j) ? 1.f : 0.f; \
                     ax = fmaf(c, tj.x, ax); ay = fmaf(c, tj.y, ay); }
        ACC(1, t1)  ACC(2, t2)  ACC(3, t3)  ACC(4, t4)  ACC(5, t5)
        ACC(6, t6)  ACC(7, t7)  ACC(8, t8)  ACC(9, t9)  ACC(10, t10)
        ACC(11, t11) ACC(12, t12) ACC(13, t13) ACC(14, t14) ACC(15, t15)
#undef ACC
      }
      my = nxt;
    }
  }
  aggb32[(size_t)n * 64 + lane] = (unsigned int)f2bf(ax) | ((unsigned int)f2bf(ay) << 16);
}

// MFMA projection: C[N,256] = aggb[N,128] @ W^T + b.
__global__ __launch_bounds__(256) void project_mfma(
    const unsigned short* __restrict__ aggb, const unsigned short* __restrict__ Bpack,
    const float* __restrict__ bias, float* __restrict__ out, int N) {
  const int wave = threadIdx.x >> 6;
  const int lane = threadIdx.x & 63;
  const int r  = lane & 15;
  const int kb = lane >> 4;
  const int m0 = blockIdx.x * 16;

  bf16x8 a[4];
  const unsigned short* arow = aggb + (size_t)(m0 + r) * IN_CH + kb * 8;
#pragma unroll
  for (int ks = 0; ks < 4; ++ks)
    a[ks] = *(const bf16x8*)(arow + ks * 32);

  f32x4 acc[4];
#pragma unroll
  for (int ct = 0; ct < 4; ++ct) acc[ct] = (f32x4){0.f, 0.f, 0.f, 0.f};

#pragma unroll
  for (int ct = 0; ct < 4; ++ct) {
    const int tn = wave * 4 + ct;
#pragma unroll
    for (int ks = 0; ks < 4; ++ks) {
      const bf16x8 b = *(const bf16x8*)(Bpack + (size_t)((((tn * 4 + ks) * 4 + kb) * 16 + r) * 8));
      acc[ct] = __builtin_amdgcn_mfma_f32_16x16x32_bf16(a[ks], b, acc[ct], 0, 0, 0);
    }
  }

#pragma unroll
  for (int ct = 0; ct < 4; ++ct) {
    const int col = wave * 64 + ct * 16 + r;
    const float bv = bias[col];
#pragma unroll
    for (int j = 0; j < 4; ++j) {
      const int m = m0 + kb * 4 + j;
      if (m < N) out[(size_t)m * OUT_CH + col] = acc[ct][j] + bv;
    }
  }
}

extern "C" void kernel_launch(void* const* d_in, const int* in_sizes, int n_in,
                              void* d_out, int out_size, void* d_ws, size_t ws_size,
                              hipStream_t stream) {
  const int* edge_index = (const int*)d_in[0];
  const float* te       = (const float*)d_in[1];
  const float* W        = (const float*)d_in[3];
  const float* bias     = (const float*)d_in[4];
  float* out            = (float*)d_out;

  const int E = in_sizes[0] / 2;
  const int N = out_size / OUT_CH;
  const int* col = edge_index + E;

  const int Np = (N + 3) & ~3;
  const int Ep = (E + 3) & ~3;
  int* ws      = (int*)d_ws;
  int* count   = ws;                          // Np
  int* offsets = ws + Np;                     // Np
  int* cursor  = ws + 2 * Np;                 // Np
  int* bsum    = ws + 3 * Np;                 // 4096
  int* sorted  = ws + 3 * Np + 4096;          // Ep
  unsigned short* Bpack = (unsigned short*)(ws + 3 * Np + 4096 + Ep);        // 32768 ushort
  unsigned int*   aggb  = (unsigned int*)(ws + 3 * Np + 4096 + Ep + 16384);  // N*64 uint

  const int nb = (N + BLK_SCAN - 1) / BLK_SCAN;
  const int init_n = (N > IN_CH * OUT_CH) ? N : IN_CH * OUT_CH;

  hipLaunchKernelGGL(init_kernel, dim3((init_n + 255) / 256), dim3(256), 0, stream,
                     W, Bpack, count, N);
  hipLaunchKernelGGL(hist_kernel, dim3((E / 4 + 255) / 256), dim3(256), 0, stream, col, E, count);
  hipLaunchKernelGGL(scan_block_kernel, dim3(nb), dim3(BLK_SCAN), 0, stream, count, N, offsets, bsum);
  hipLaunchKernelGGL(scan_bsum_kernel, dim3(1), dim3(256), 0, stream, bsum, nb);
  hipLaunchKernelGGL(add_offsets_kernel, dim3((N + 255) / 256), dim3(256), 0, stream,
                     offsets, bsum, cursor, N);
  hipLaunchKernelGGL(scatter_kernel, dim3((E / 4 + 255) / 256), dim3(256), 0, stream,
                     col, E, cursor, sorted);
  hipLaunchKernelGGL(aggregate_kernel, dim3((N + 3) / 4), dim3(256), 0, stream,
                     te, offsets, cursor, sorted, aggb, N);
  hipLaunchKernelGGL(project_mfma, dim3((N + 15) / 16), dim3(256), 0, stream,
                     (const unsigned short*)aggb, Bpack, bias, out, N);
}